// Round 2
// 300.860 us; speedup vs baseline: 1.0115x; 1.0115x over previous
//
#include <hip/hip_runtime.h>

#define NEG_SLOPE 0.2f
#define NPB 256          // nodes per dst-bucket (bucket = dst >> 8)
#define CHUNK 4096       // edges per partition block

typedef _Float16 f16x8 __attribute__((ext_vector_type(8)));
typedef _Float16 f16x4 __attribute__((ext_vector_type(4)));
typedef _Float16 f16x2 __attribute__((ext_vector_type(2)));
typedef float    f32x4 __attribute__((ext_vector_type(4)));
typedef float    f32x8 __attribute__((ext_vector_type(8)));

#if defined(__has_builtin)
#if __has_builtin(__builtin_amdgcn_fdot2)
#define HAVE_FDOT2 1
#endif
#endif

__device__ __forceinline__ f32x8 cvt8(f16x8 v) {
    return __builtin_convertvector(v, f32x8);
}

// DPP butterfly add step — pure VALU, no LDS pipe (vs __shfl_xor's ds_bpermute).
// CTRL: 0xB1 = quad_perm(1,0,3,2) (xor1), 0x4E = quad_perm(2,3,0,1) (xor2),
// 0x141 = row_half_mirror (xor4 once quads uniform), 0x140 = row_mirror (xor8
// once 8-groups uniform). CTRL must be a compile-time constant -> template.
template <int CTRL>
__device__ __forceinline__ float dpp_add(float v) {
    int o = __builtin_amdgcn_update_dpp(0, __builtin_bit_cast(int, v),
                                        CTRL, 0xF, 0xF, true);
    return v + __builtin_bit_cast(float, o);
}

// ---------------------------------------------------------------------------
// prep: W transpose->fp16 (blocks 0..255), x fp32->fp16 hi/lo split
// (blocks 256..), bcnt zero (block 0).
// ---------------------------------------------------------------------------
__global__ __launch_bounds__(256) void prep_kernel(
    const float* __restrict__ W0, const float* __restrict__ W1,
    const float* __restrict__ W2, const float* __restrict__ W3,
    _Float16* __restrict__ wt,
    const float* __restrict__ x, _Float16* __restrict__ xh,
    _Float16* __restrict__ xlo, int total, int* __restrict__ bcnt)
{
    int t = threadIdx.x;
    if (blockIdx.x < 256) {
        if (blockIdx.x == 0) bcnt[t] = 0;
        int idx = blockIdx.x * 256 + t;     // 4*128*128
        int m = idx >> 14;
        int k = (idx >> 7) & 127;
        int n = idx & 127;
        const float* W = (m == 0) ? W0 : (m == 1) ? W1 : (m == 2) ? W2 : W3;
        wt[m * 16384 + n * 128 + k] = (_Float16)W[k * 128 + n];
    } else {
        int i = (blockIdx.x - 256) * 256 + t;
        if (i * 2 < total) {
            float2 f = *(const float2*)(x + (size_t)i * 2);
            _Float16 h0 = (_Float16)f.x, h1 = (_Float16)f.y;
            _Float16 l0 = (_Float16)(f.x - (float)h0), l1 = (_Float16)(f.y - (float)h1);
            *(f16x2*)(xh  + (size_t)i * 2) = (f16x2){h0, h1};
            *(f16x2*)(xlo + (size_t)i * 2) = (f16x2){l0, l1};
        }
    }
}

// ---------------------------------------------------------------------------
// fp16 MFMA GEMM, LDS-staged W (34 KB). C = Ah@W + Al@W, fp32 acc.
// Both outputs stored fp16 (y==0 -> Cl, y==1 -> Cr).
// ---------------------------------------------------------------------------
__global__ __launch_bounds__(256) void gemm_f16_kernel(
    const _Float16* __restrict__ Ahi, const _Float16* __restrict__ Alo,
    const _Float16* __restrict__ Wt0, const _Float16* __restrict__ Wt1,
    _Float16* __restrict__ Cl, _Float16* __restrict__ Cr, int N)
{
    const _Float16* Wt = blockIdx.y ? Wt1 : Wt0;
    _Float16* C = blockIdx.y ? Cr : Cl;

    __shared__ _Float16 ldsW[128 * 136];   // row stride 272 B

    const int tid = threadIdx.x;
    const int wave = tid >> 6;
    const int lane = tid & 63;
    const int mrow = lane & 15;
    const int quad = lane >> 4;
    const int rbase = blockIdx.x * 128 + wave * 32;

    // staging loads first (latency overlaps A loads)
    const int sn = tid >> 1, shf = tid & 1;
    float4 stg[8];
    {
        const float4* g = (const float4*)(Wt + sn * 128 + shf * 64);
#pragma unroll
        for (int j = 0; j < 8; j++) stg[j] = g[j];
    }

    f16x8 ah[2][4], al[2][4];
#pragma unroll
    for (int rt = 0; rt < 2; rt++) {
        int r = rbase + rt * 16 + mrow;
        if (r > N - 1) r = N - 1;
        const _Float16* pa = Ahi + (size_t)r * 128 + quad * 8;
        const _Float16* pl = Alo + (size_t)r * 128 + quad * 8;
#pragma unroll
        for (int s = 0; s < 4; s++) {
            ah[rt][s] = *(const f16x8*)(pa + s * 32);
            al[rt][s] = *(const f16x8*)(pl + s * 32);
        }
    }

    {
        float4* d = (float4*)&ldsW[sn * 136 + shf * 64];
#pragma unroll
        for (int j = 0; j < 8; j++) d[j] = stg[j];
    }

    f32x4 acc[2][8];
#pragma unroll
    for (int rt = 0; rt < 2; rt++)
#pragma unroll
        for (int c = 0; c < 8; c++) acc[rt][c] = (f32x4){0.f, 0.f, 0.f, 0.f};

    __syncthreads();

#pragma unroll
    for (int s = 0; s < 4; s++) {
#pragma unroll
        for (int c = 0; c < 8; c++) {
            f16x8 bw = *(const f16x8*)&ldsW[(c * 16 + mrow) * 136 + s * 32 + quad * 8];
            acc[0][c] = __builtin_amdgcn_mfma_f32_16x16x32_f16(ah[0][s], bw, acc[0][c], 0, 0, 0);
            acc[0][c] = __builtin_amdgcn_mfma_f32_16x16x32_f16(al[0][s], bw, acc[0][c], 0, 0, 0);
            acc[1][c] = __builtin_amdgcn_mfma_f32_16x16x32_f16(ah[1][s], bw, acc[1][c], 0, 0, 0);
            acc[1][c] = __builtin_amdgcn_mfma_f32_16x16x32_f16(al[1][s], bw, acc[1][c], 0, 0, 0);
        }
    }

    // D mapping: col = lane&15, row = quad*4 + reg
#pragma unroll
    for (int rt = 0; rt < 2; rt++)
#pragma unroll
        for (int i = 0; i < 4; i++) {
            int r = rbase + rt * 16 + quad * 4 + i;
            if (r < N) {
                _Float16* cr = C + (size_t)r * 128 + mrow;
#pragma unroll
                for (int c = 0; c < 8; c++) cr[c * 16] = (_Float16)acc[rt][c][i];
            }
        }
}

// ---------------------------------------------------------------------------
// Bucketed CSR build (bucket = dst>>8): writes stay CU/XCD-local.
// ---------------------------------------------------------------------------
__global__ __launch_bounds__(256) void histB_kernel(
    const int* __restrict__ ei, int* __restrict__ bcnt, int E)
{
    __shared__ int bh[256];
    int t = threadIdx.x;
    bh[t] = 0;
    __syncthreads();
    int base = blockIdx.x * CHUNK;
#pragma unroll
    for (int j = 0; j < CHUNK / 256; j++) {
        int e = base + t + j * 256;
        if (e < E) atomicAdd(&bh[ei[E + e] >> 8], 1);
    }
    __syncthreads();
    if (bh[t]) atomicAdd(&bcnt[t], bh[t]);
}

__global__ __launch_bounds__(256) void scanB_kernel(
    const int* __restrict__ bcnt, int* __restrict__ bstart,
    int* __restrict__ gcursor, int NB, int E)
{
    __shared__ int s[256];
    int t = threadIdx.x;
    int v = (t < NB) ? bcnt[t] : 0;
    s[t] = v;
    __syncthreads();
    for (int off = 1; off < 256; off <<= 1) {
        int u = (t >= off) ? s[t - off] : 0;
        __syncthreads();
        s[t] += u;
        __syncthreads();
    }
    if (t < NB) { bstart[t] = s[t] - v; gcursor[t] = s[t] - v; }
    if (t == 0) bstart[NB] = E;
}

__global__ __launch_bounds__(256) void passA_kernel(
    const int* __restrict__ ei, int* __restrict__ gcursor,
    int2* __restrict__ staging, int E)
{
    __shared__ int bh[256];
    __shared__ int bbase[256];
    int t = threadIdx.x;
    bh[t] = 0;
    __syncthreads();
    int base = blockIdx.x * CHUNK;
    int srcv[16], dstv[16], rb[16];
#pragma unroll
    for (int j = 0; j < 16; j++) {
        int e = base + t + j * 256;
        if (e < E) {
            int d = ei[E + e];
            srcv[j] = ei[e];
            dstv[j] = d;
            int bk = d >> 8;
            int r = atomicAdd(&bh[bk], 1);
            rb[j] = (r << 8) | bk;
        } else rb[j] = -1;
    }
    __syncthreads();
    if (bh[t]) bbase[t] = atomicAdd(&gcursor[t], bh[t]);
    __syncthreads();
#pragma unroll
    for (int j = 0; j < 16; j++) {
        if (rb[j] >= 0) {
            int bk = rb[j] & 255, r = rb[j] >> 8;
            staging[bbase[bk] + r] = make_int2(srcv[j], dstv[j]);
        }
    }
}

__global__ __launch_bounds__(256) void passB_kernel(
    const int2* __restrict__ staging, const int* __restrict__ bstart,
    int* __restrict__ start, int* __restrict__ sorted_src, int N, int E)
{
    __shared__ int lhist[256], lscan[256], lcur[256];
    int b = blockIdx.x, t = threadIdx.x;
    int r0 = bstart[b], r1 = bstart[b + 1];
    lhist[t] = 0;
    __syncthreads();
    for (int i = r0 + t; i < r1; i += 256) atomicAdd(&lhist[staging[i].y & 255], 1);
    __syncthreads();
    int v = lhist[t];
    lscan[t] = v;
    __syncthreads();
    for (int off = 1; off < 256; off <<= 1) {
        int u = (t >= off) ? lscan[t - off] : 0;
        __syncthreads();
        lscan[t] += u;
        __syncthreads();
    }
    int excl = lscan[t] - v;
    int node = b * NPB + t;
    if (node < N) start[node] = r0 + excl;
    lcur[t] = excl;
    if (b == 0 && t == 0) start[N] = E;
    __syncthreads();
    for (int i = r0 + t; i < r1; i += 256) {
        int2 p = staging[i];
        int rank = atomicAdd(&lcur[p.y & 255], 1);
        sorted_src[r0 + rank] = p.x;
    }
}

// ---------------------------------------------------------------------------
// Fused score+softmax+aggregate.
// One wave per dst node; 16 lanes per edge (f16x8/lane), 4 edges per wave-op.
// Score reduction entirely via DPP (no ds_bpermute in the inner loop):
//   xor1 (quad_perm 0xB1), xor2 (quad_perm 0x4E), xor4 (row_half_mirror,
//   valid once quads are uniform), xor8 (row_mirror, valid once 8-groups are
//   uniform). H==2 stops after 3 steps: lanes 0-7 = head 0, 8-15 = head 1,
//   so each 8-lane subgroup holds its own head's score/denominator.
// att pre-scaled by log2(e) -> exp2f. Self-loop = virtual edge 0.
// ---------------------------------------------------------------------------
template <int H, bool BFOUT>
__global__ __launch_bounds__(256) void gat_fused_kernel(
    const _Float16* __restrict__ xl, const _Float16* __restrict__ xr,
    const float* __restrict__ att, const float* __restrict__ bias,
    const int* __restrict__ start, const int* __restrict__ sorted_src,
    float* __restrict__ outf, _Float16* __restrict__ oh,
    _Float16* __restrict__ ol, int N)
{
    int node = blockIdx.x * 4 + (threadIdx.x >> 6);
    if (node >= N) return;
    const int lane = threadIdx.x & 63;
    const int g  = lane >> 4;          // edge slot 0..3
    const int hl = lane & 15;          // feature slot: ch [hl*8, hl*8+8)
    const _Float16 NS = (_Float16)NEG_SLOPE;
    const float L2E = 1.44269504f;

    const f16x8 b4 = *(const f16x8*)(xr + (size_t)node * 128 + hl * 8);
    float4 at0 = *(const float4*)(att + hl * 8);
    float4 at1 = *(const float4*)(att + hl * 8 + 4);
#if defined(HAVE_FDOT2)
    f16x2 av0 = {(_Float16)(at0.x * L2E), (_Float16)(at0.y * L2E)};
    f16x2 av1 = {(_Float16)(at0.z * L2E), (_Float16)(at0.w * L2E)};
    f16x2 av2 = {(_Float16)(at1.x * L2E), (_Float16)(at1.y * L2E)};
    f16x2 av3 = {(_Float16)(at1.z * L2E), (_Float16)(at1.w * L2E)};
#else
    f32x8 avf = {at0.x * L2E, at0.y * L2E, at0.z * L2E, at0.w * L2E,
                 at1.x * L2E, at1.y * L2E, at1.z * L2E, at1.w * L2E};
#endif

    auto score = [&](f16x8 a_) -> float {
        f16x8 t = a_ + b4;
        f16x8 u = __builtin_elementwise_max(t, t * NS);
#if defined(HAVE_FDOT2)
        f16x2 u0 = __builtin_shufflevector(u, u, 0, 1);
        f16x2 u1 = __builtin_shufflevector(u, u, 2, 3);
        f16x2 u2 = __builtin_shufflevector(u, u, 4, 5);
        f16x2 u3 = __builtin_shufflevector(u, u, 6, 7);
        return __builtin_amdgcn_fdot2(u0, av0,
               __builtin_amdgcn_fdot2(u1, av1,
               __builtin_amdgcn_fdot2(u2, av2,
               __builtin_amdgcn_fdot2(u3, av3, 0.f, false), false), false), false);
#else
        f32x8 uf = cvt8(u);
        float p = 0.f;
#pragma unroll
        for (int i = 0; i < 8; i++) p += uf[i] * avf[i];
        return p;
#endif
    };

    // 16-lane (or 8-lane for H==2) butterfly reduce, pure DPP.
    auto red = [&](float p) -> float {
        p = dpp_add<0xB1>(p);            // xor1
        p = dpp_add<0x4E>(p);            // xor2
        p = dpp_add<0x141>(p);           // xor4 (row_half_mirror)
        if (H == 1) p = dpp_add<0x140>(p);   // xor8 (row_mirror)
        return p;
    };

    f32x8 acc = {0.f, 0.f, 0.f, 0.f, 0.f, 0.f, 0.f, 0.f};
    float den = 0.f;

    const int s0 = start[node];
    const int s1 = start[node + 1];
    const int M  = s1 - s0 + 1;        // incl. self-loop at iv==0
    const int Kfull = M >> 2;          // full 4-edge iterations
    const int K     = (M + 3) >> 2;

#define GBODY(B) {                                                          \
        int srcv[B]; f16x8 a[B]; float p[B];                                \
        _Pragma("unroll")                                                   \
        for (int j = 0; j < B; j++) {                                       \
            int iv = 4 * (k + j) + g;                                       \
            int ld = sorted_src[s0 + ((iv > 0) ? iv - 1 : 0)];              \
            srcv[j] = (iv == 0) ? node : ld;                                \
        }                                                                   \
        _Pragma("unroll")                                                   \
        for (int j = 0; j < B; j++)                                         \
            a[j] = *(const f16x8*)(xl + (size_t)srcv[j] * 128 + hl * 8);    \
        _Pragma("unroll")                                                   \
        for (int j = 0; j < B; j++) p[j] = score(a[j]);                     \
        _Pragma("unroll")                                                   \
        for (int j = 0; j < B; j++) p[j] = red(p[j]);                       \
        _Pragma("unroll")                                                   \
        for (int j = 0; j < B; j++) {                                       \
            float e = exp2f(p[j]);                                          \
            den += e;                                                       \
            acc = acc + cvt8(a[j]) * e;                                     \
        }                                                                   \
    }

    int k = 0;
    for (; k + 4 <= Kfull; k += 4) GBODY(4)       // 16 edges in flight
    if (k + 2 <= Kfull) { GBODY(2) k += 2; }      // 8 edges
    if (k < Kfull)      { GBODY(1) k += 1; }      // 4 edges
    if (k < K) {                                  // masked tail (<=1 iter)
        int iv = 4 * k + g;
        bool valid = iv < M;                      // uniform within 16-lane group
        int ld = sorted_src[s0 + ((iv > 0) ? iv - 1 : 0)];  // padded array
        int src = (iv == 0) ? node : (valid ? ld : node);
        f16x8 a = *(const f16x8*)(xl + (size_t)src * 128 + hl * 8);
        float p = red(score(a));
        float e = valid ? exp2f(p) : 0.f;
        den += e;
        acc = acc + cvt8(a) * e;
    }
#undef GBODY

    // combine the 4 edge-groups (feature-aligned): masks 16 and 32 only.
    den += __shfl_xor(den, 16, 64);
    den += __shfl_xor(den, 32, 64);
#pragma unroll
    for (int i = 0; i < 8; i++) {
        acc[i] += __shfl_xor(acc[i], 16, 64);
        acc[i] += __shfl_xor(acc[i], 32, 64);
    }

    float inv = 1.0f / den;
    float4 bi0 = *(const float4*)(bias + hl * 8);
    float4 bi1 = *(const float4*)(bias + hl * 8 + 4);
    float o[8];
    o[0] = acc[0] * inv + bi0.x;  o[1] = acc[1] * inv + bi0.y;
    o[2] = acc[2] * inv + bi0.z;  o[3] = acc[3] * inv + bi0.w;
    o[4] = acc[4] * inv + bi1.x;  o[5] = acc[5] * inv + bi1.y;
    o[6] = acc[6] * inv + bi1.z;  o[7] = acc[7] * inv + bi1.w;

    if (lane < 16) {
        if (BFOUT) {   // next layer's A: fp16 hi+lo split
            f16x8 hv, lv;
#pragma unroll
            for (int i = 0; i < 8; i++) {
                _Float16 h = (_Float16)o[i];
                hv[i] = h;
                lv[i] = (_Float16)(o[i] - (float)h);
            }
            *(f16x8*)(oh + (size_t)node * 128 + hl * 8) = hv;
            *(f16x8*)(ol + (size_t)node * 128 + hl * 8) = lv;
        } else {
            *(float4*)(outf + (size_t)node * 128 + hl * 8) =
                make_float4(o[0], o[1], o[2], o[3]);
            *(float4*)(outf + (size_t)node * 128 + hl * 8 + 4) =
                make_float4(o[4], o[5], o[6], o[7]);
        }
    }
}

// ---------------------------------------------------------------------------
extern "C" void kernel_launch(void* const* d_in, const int* in_sizes, int n_in,
                              void* d_out, int out_size, void* d_ws, size_t ws_size,
                              hipStream_t stream)
{
    const float* x    = (const float*)d_in[0];
    const int*   ei   = (const int*)d_in[1];
    const float* Wl1  = (const float*)d_in[3];
    const float* Wr1  = (const float*)d_in[4];
    const float* att1 = (const float*)d_in[5];
    const float* b1   = (const float*)d_in[6];
    const float* Wl2  = (const float*)d_in[7];
    const float* Wr2  = (const float*)d_in[8];
    const float* att2 = (const float*)d_in[9];
    const float* b2   = (const float*)d_in[10];
    float* out = (float*)d_out;

    const int N  = in_sizes[0] / 128;
    const int E  = in_sizes[1] / 2;
    const int NB = (N + NPB - 1) / NPB;

    const size_t nf = (size_t)N * 128;
    _Float16* xlf  = (_Float16*)d_ws;                 // nf fp16 (gather array)
    _Float16* xrf  = xlf + nf;                        // nf fp16
    _Float16* ah   = xrf + nf;                        // nf fp16 (A hi: x, then h)
    _Float16* al   = ah + nf;                         // nf fp16 (A lo)
    _Float16* wt   = al + nf;                         // 4*16384 fp16
    int* bcnt      = (int*)(wt + 4 * 16384);          // 256
    int* bstart    = bcnt + 256;                      // NB+1 (<=257)
    int* gcursor   = bstart + 257;                    // 256
    int* start     = gcursor + 256;                   // N+1
    size_t stgoff  = ((size_t)(start + N + 1) + 7) & ~(size_t)7;
    int2* staging  = (int2*)stgoff;                   // E int2
    int* sorted_src = (int*)(staging + E);            // E + 64 (padded)

    const int grid_chunk = (E + CHUNK - 1) / CHUNK;
    const int node_grid  = (N + 3) / 4;
    const int gemm_gx    = (N + 127) / 128;
    const int split_grid = (int)((nf / 2 + 255) / 256);

    // ---- prep: W->fp16 transposed, x split, bcnt zero ----
    prep_kernel<<<256 + split_grid, 256, 0, stream>>>(
        Wl1, Wr1, Wl2, Wr2, wt, x, ah, al, (int)nf, bcnt);

    // ---- bucketed CSR build (shared by both layers) ----
    histB_kernel<<<grid_chunk, 256, 0, stream>>>(ei, bcnt, E);
    scanB_kernel<<<1, 256, 0, stream>>>(bcnt, bstart, gcursor, NB, E);
    passA_kernel<<<grid_chunk, 256, 0, stream>>>(ei, gcursor, staging, E);
    passB_kernel<<<NB, 256, 0, stream>>>(staging, bstart, start, sorted_src, N, E);

    // ---- Layer 1: heads=2, ch=64 ----
    gemm_f16_kernel<<<dim3(gemm_gx, 2), 256, 0, stream>>>(
        ah, al, wt + 0 * 16384, wt + 1 * 16384, xlf, xrf, N);
    gat_fused_kernel<2, true><<<node_grid, 256, 0, stream>>>(
        xlf, xrf, att1, b1, start, sorted_src, nullptr, ah, al, N);

    // ---- Layer 2: heads=1, ch=128 ----
    gemm_f16_kernel<<<dim3(gemm_gx, 2), 256, 0, stream>>>(
        ah, al, wt + 2 * 16384, wt + 3 * 16384, xlf, xrf, N);
    gat_fused_kernel<1, false><<<node_grid, 256, 0, stream>>>(
        xlf, xrf, att2, b2, start, sorted_src, out, nullptr, nullptr, N);
}